// Round 5
// baseline (936.301 us; speedup 1.0000x reference)
//
#include <hip/hip_runtime.h>
#include <stdint.h>

#define NB 8
#define NP 4096
#define NS 1024
#define NK 64
#define ND 64
#define NH 64
#define NCO 128

#define FPS_T 512
#define PPT (NP / FPS_T)   // 8 points per thread

// padded K strides (in halves) for conflict-free b128 LDS access
#define K1P 104            // layer1 K: 64 x-ch + 3 xyz + zeros to 96, padded to 104
#define K2P 72             // layer2/3 K: 64, padded to 72

#define QPB 16             // queries per block in mlp_kernel

typedef _Float16 half8v __attribute__((ext_vector_type(8)));
typedef _Float16 half4v __attribute__((ext_vector_type(4)));
typedef _Float16 half2v __attribute__((ext_vector_type(2)));
typedef float    floatx4 __attribute__((ext_vector_type(4)));

// DPP move helper (ctrl must be compile-time constant)
template <int CTRL>
__device__ __forceinline__ float dpp_mov_f32(float x) {
    return __int_as_float(__builtin_amdgcn_update_dpp(
        0, __float_as_int(x), CTRL, 0xf, 0xf, true));
}

// select arr[j] from an 8-element register array, j in [0,8)
#define SEL8(arr, j) ({                                   \
    float _t0 = ((j) & 1) ? arr[1] : arr[0];              \
    float _t1 = ((j) & 1) ? arr[3] : arr[2];              \
    float _t2 = ((j) & 1) ? arr[5] : arr[4];              \
    float _t3 = ((j) & 1) ? arr[7] : arr[6];              \
    float _u0 = ((j) & 2) ? _t1 : _t0;                    \
    float _u1 = ((j) & 2) ? _t3 : _t2;                    \
    ((j) & 4) ? _u1 : _u0; })

// ---------------- Kernel 0: weight transpose + f16 convert ----------------
// wt layout (halves): [0)      W1t[64][104]: k<64 -> W1[(3+k)*64+j] (x chans),
//                              k=64..66 -> W1[(k-64)*64+j] (xyz), else 0
//                     [6656)   W2t[64][72]:  k<64 -> W2[k*64+r], else 0
//                     [11264)  W3t[128][72]: k<64 -> W3[k*128+r], else 0
__global__ __launch_bounds__(64) void wt_kernel(const float* __restrict__ W1,
                                                const float* __restrict__ W2,
                                                const float* __restrict__ W3,
                                                _Float16* __restrict__ wt)
{
    const int j = blockIdx.x;
    const int t = threadIdx.x;
    if (j < 64) {
        for (int k = t; k < K1P; k += 64) {
            float v = 0.f;
            if (k < 64)       v = W1[(3 + k) * 64 + j];
            else if (k < 67)  v = W1[(k - 64) * 64 + j];
            wt[j * K1P + k] = (_Float16)v;
        }
    } else if (j < 128) {
        const int r = j - 64;
        for (int k = t; k < K2P; k += 64) {
            float v = (k < 64) ? W2[k * 64 + r] : 0.f;
            wt[6656 + r * K2P + k] = (_Float16)v;
        }
    } else {
        const int r = j - 128;
        for (int k = t; k < K2P; k += 64) {
            float v = (k < 64) ? W3[k * 128 + r] : 0.f;
            wt[11264 + r * K2P + k] = (_Float16)v;
        }
    }
}

// ---------------- Kernel 1: farthest point sampling ----------------
// One block per batch, 512 threads, 8 points/thread in registers.
// Bit-exact fp32 (contract off) so argmax selections match the reference.
// Winner coords flow through registers/cbuf (no dependent sp[last] read):
// each wave's winner lane writes {key, coords} pre-barrier; post-barrier the
// u64-key tree picks the global winner and coords are broadcast via readlane.
__global__ __launch_bounds__(FPS_T) void fps_kernel(const float* __restrict__ pos,
                                                    float* __restrict__ new_xyz)
{
#pragma clang fp contract(off)
    const int b    = blockIdx.x;
    const int tid  = threadIdx.x;
    const int lane = tid & 63;
    const int wv   = tid >> 6;            // 0..7

    __shared__ alignas(16) unsigned long long kbuf[2][8];
    __shared__ alignas(16) float4 cbuf[2][8];

    const float* p = pos + (size_t)b * NP * 3;

    float px[PPT], py[PPT], pz[PPT], md[PPT];
#pragma unroll
    for (int j = 0; j < PPT; ++j) {
        const int idx = tid * PPT + j;
        px[j] = p[idx * 3 + 0];
        py[j] = p[idx * 3 + 1];
        pz[j] = p[idx * 3 + 2];
        md[j] = 1e10f;
    }

    // step 0: point 0 (broadcast read, cached)
    float lx = p[0], ly = p[1], lz = p[2];
    if (tid == 0) {
        float* o = new_xyz + (size_t)b * NS * 3;
        o[0] = lx; o[1] = ly; o[2] = lz;
    }

    int par = 0;
    for (int s = 1; s < NS; ++s) {
        // local update + argmax (strict >, ascending idx => first-index ties).
        // all md >= 0, so bv=0 init is exact.
        float bv = 0.0f;
        int   bi = tid * PPT;
#pragma unroll
        for (int j = 0; j < PPT; ++j) {
            float dx = px[j] - lx;
            float dy = py[j] - ly;
            float dz = pz[j] - lz;
            float d2 = dx * dx + dy * dy + dz * dz;   // contract(off): exact IEEE
            float m  = (md[j] < d2) ? md[j] : d2;     // jnp.minimum
            md[j] = m;
            if (m > bv) { bv = m; bi = tid * PPT + j; }
        }

        // wave max of bv via DPP (values >= 0 so zero-fill is identity);
        // full-wave max lands in lane 63.
        float r = bv;
        r = fmaxf(r, dpp_mov_f32<0x111>(r));   // row_shr:1
        r = fmaxf(r, dpp_mov_f32<0x112>(r));   // row_shr:2
        r = fmaxf(r, dpp_mov_f32<0x114>(r));   // row_shr:4
        r = fmaxf(r, dpp_mov_f32<0x118>(r));   // row_shr:8
        r = fmaxf(r, dpp_mov_f32<0x142>(r));   // row_bcast:15
        r = fmaxf(r, dpp_mov_f32<0x143>(r));   // row_bcast:31
        const float gmax = __int_as_float(
            __builtin_amdgcn_readlane(__float_as_int(r), 63));

        // first lane achieving gmax = smallest achieving index in this wave;
        // that lane writes key + its winning point's coords (register select).
        unsigned long long mk = __ballot(bv == gmax);
        int wl = (int)__builtin_ctzll(mk);
        if (lane == wl) {
            const int j = bi & (PPT - 1);
            kbuf[par][wv] =
                ((unsigned long long)__float_as_uint(bv) << 32) |
                (unsigned long long)(~(unsigned)bi);
            cbuf[par][wv] = make_float4(SEL8(px, j), SEL8(py, j), SEL8(pz, j), 0.f);
        }
        __syncthreads();

        // keys tree (redundant in every thread) + overlapped coords read
        const ulonglong2* kb = (const ulonglong2*)kbuf[par];
        float4 cc = cbuf[par][lane & 7];
        ulonglong2 q0 = kb[0], q1 = kb[1], q2 = kb[2], q3 = kb[3];
        unsigned long long a0 = (q0.y > q0.x) ? q0.y : q0.x;
        unsigned long long a1 = (q1.y > q1.x) ? q1.y : q1.x;
        unsigned long long a2 = (q2.y > q2.x) ? q2.y : q2.x;
        unsigned long long a3 = (q3.y > q3.x) ? q3.y : q3.x;
        unsigned long long b0 = (a1 > a0) ? a1 : a0;
        unsigned long long b1 = (a3 > a2) ? a3 : a2;
        unsigned long long g  = (b1 > b0) ? b1 : b0;

        const int last = (int)(~(unsigned)g);
        const int w    = last >> 9;              // winning wave (512 pts/wave)
        const int ws   = __builtin_amdgcn_readfirstlane(w);
        lx = __int_as_float(__builtin_amdgcn_readlane(__float_as_int(cc.x), ws));
        ly = __int_as_float(__builtin_amdgcn_readlane(__float_as_int(cc.y), ws));
        lz = __int_as_float(__builtin_amdgcn_readlane(__float_as_int(cc.z), ws));

        if (tid == 0) {
            float* o = new_xyz + ((size_t)b * NS + s) * 3;
            o[0] = lx; o[1] = ly; o[2] = lz;
        }
        par ^= 1;
    }
}

// ---------------- Kernel 2: ball query (int16 output) ----------------
__global__ __launch_bounds__(256) void ballq_kernel(const float* __restrict__ pos,
                                                    const float* __restrict__ new_xyz,
                                                    short* __restrict__ ball_idx)
{
#pragma clang fp contract(off)
    const int lane = threadIdx.x & 63;
    const int q    = (blockIdx.x * 256 + threadIdx.x) >> 6;   // 0..NB*NS-1
    const int b    = q >> 10;

    const float* p  = pos + (size_t)b * NP * 3;
    const float  qx = new_xyz[q * 3 + 0];
    const float  qy = new_xyz[q * 3 + 1];
    const float  qz = new_xyz[q * 3 + 2];
    short* outp = ball_idx + (size_t)q * NK;

    int cnt = 0;
    for (int n0 = 0; n0 < NP; n0 += 64) {
        const int n = n0 + lane;
        float dx = qx - p[n * 3 + 0];
        float dy = qy - p[n * 3 + 1];
        float dz = qz - p[n * 3 + 2];
        float d2 = dx * dx + dy * dy + dz * dz;   // contract(off)
        bool within = d2 < 0.04f;                 // r^2, strict <
        unsigned long long m = __ballot(within);
        if (within) {
            int slot = cnt + __popcll(m & ((1ull << lane) - 1ull));
            if (slot < NK) outp[slot] = (short)n;
        }
        cnt += (int)__popcll(m);
        if (cnt >= NK) break;
    }
    if (cnt < NK) {
        if (lane < NK - cnt) outp[cnt + lane] = (short)-1;
    }
}

// ---------------- Kernel 3: persistent gather + f16-MFMA MLP + max-pool ------
// 512 blocks x QPB(16) queries. All 36 weight frags hoisted to registers once
// per block (loaded straight from global wt). Layers 1/2: h^T = W^T x act^T
// (C/D col = neighbor -> packed b64 writes). Layer 3 swaps MFMA operands
// (act as A, W3 as B) so C/D rows = neighbors: pool = 3 in-register fmax +
// xor16/xor32 shuffles. Bias postponed past the pool (exact: fp max/add
// monotone); masked-0 restored via fmax(m,0) when the nbr list has padding.
__global__ __launch_bounds__(256, 2) void mlp_kernel(const float* __restrict__ x,
        const float* __restrict__ pos,
        const float* __restrict__ b1, const float* __restrict__ b2,
        const float* __restrict__ b3,
        const float* __restrict__ new_xyz, const short* __restrict__ ball_idx,
        const _Float16* __restrict__ wt,
        float* __restrict__ out)
{
    const int tid  = threadIdx.x;
    const int lane = tid & 63;
    const int wv   = tid >> 6;
    const int qd   = lane >> 4;       // quad
    const int c    = lane & 15;       // col within MFMA tile
    const int myrow = wv * 16 + c;    // this lane's neighbor row

    __shared__ alignas(16) _Float16 G [64 * K1P];   // gathered input: [nbr][k]
    __shared__ alignas(16) _Float16 H1[64 * K2P];   // h1: [nbr][ch]
    __shared__ alignas(16) _Float16 H2[64 * K2P];   // h2: [nbr][ch]
    __shared__ alignas(16) float    CW[4 * NCO];    // per-wave pooled partials
    __shared__ alignas(16) float    Lb[128];        // b1|b2 staged
    __shared__ short nbr_s[NK];

    // ---- hoist all weight fragments into registers (once per block) ----
    half8v a1[3][4], a2[2][4], a3[2][8];
#pragma unroll
    for (int ks = 0; ks < 3; ++ks)
#pragma unroll
        for (int mt = 0; mt < 4; ++mt)
            a1[ks][mt] = *(const half8v*)&wt[(mt * 16 + c) * K1P + ks * 32 + qd * 8];
#pragma unroll
    for (int ks = 0; ks < 2; ++ks)
#pragma unroll
        for (int mt = 0; mt < 4; ++mt)
            a2[ks][mt] = *(const half8v*)&wt[6656 + (mt * 16 + c) * K2P + ks * 32 + qd * 8];
#pragma unroll
    for (int ks = 0; ks < 2; ++ks)
#pragma unroll
        for (int mt = 0; mt < 8; ++mt)
            a3[ks][mt] = *(const half8v*)&wt[11264 + (mt * 16 + c) * K2P + ks * 32 + qd * 8];

    const float b3r = (tid < NCO) ? b3[tid] : 0.f;
    if (tid < 64) { Lb[tid] = b1[tid]; Lb[64 + tid] = b2[tid]; }
    {   // zero G once; gather never touches cols >= 67 (MFMA pad)
        half8v z = {};
        for (int i = tid; i < (64 * K1P) / 8; i += 256) ((half8v*)G)[i] = z;
    }

    for (int qi = 0; qi < QPB; ++qi) {
        const int bs = blockIdx.x * QPB + qi;
        const int b  = bs >> 10;

        __syncthreads();   // protect G/H/nbr_s/CW reuse from previous query

        // gather: thread -> neighbor tid>>2, x-channel quarter tid&3
        {
            const int ni = tid >> 2;
            const int p4 = tid & 3;
            const int n  = (int)ball_idx[(size_t)bs * NK + ni];
            const int nn = (n < 0) ? (NP - 1) : n;    // ref: points[-1] padding
            const float* xr = x + ((size_t)b * NP + nn) * ND + p4 * 16;
#pragma unroll
            for (int i = 0; i < 4; ++i) {
                float4 v = *(const float4*)(xr + 4 * i);
                half4v h;
                h[0] = (_Float16)v.x; h[1] = (_Float16)v.y;
                h[2] = (_Float16)v.z; h[3] = (_Float16)v.w;
                *(half4v*)&G[ni * K1P + p4 * 16 + 4 * i] = h;
            }
            if (p4 == 3) nbr_s[ni] = (short)n;
            if (p4 == 0) {
                const float* pr = pos + (size_t)(b * NP + nn) * 3;
                float gx = pr[0] - new_xyz[bs * 3 + 0];
                float gy = pr[1] - new_xyz[bs * 3 + 1];
                float gz = pr[2] - new_xyz[bs * 3 + 2];
                half2v h2; h2[0] = (_Float16)gx; h2[1] = (_Float16)gy;
                *(half2v*)&G[ni * K1P + 64] = h2;
                G[ni * K1P + 66] = (_Float16)gz;
            }
        }
        __syncthreads();

        // ---- layer 1: K=96 (3 steps), out 64 ch ----
        {
            floatx4 acc[4] = {};
#pragma unroll
            for (int ks = 0; ks < 3; ++ks) {
                half8v bf = *(const half8v*)&G[myrow * K1P + ks * 32 + qd * 8];
#pragma unroll
                for (int mt = 0; mt < 4; ++mt)
                    acc[mt] = __builtin_amdgcn_mfma_f32_16x16x32_f16(a1[ks][mt], bf, acc[mt], 0, 0, 0);
            }
#pragma unroll
            for (int mt = 0; mt < 4; ++mt) {
                float4 bb = *(const float4*)&Lb[mt * 16 + qd * 4];
                half4v h;
                h[0] = (_Float16)fmaxf(acc[mt][0] + bb.x, 0.f);
                h[1] = (_Float16)fmaxf(acc[mt][1] + bb.y, 0.f);
                h[2] = (_Float16)fmaxf(acc[mt][2] + bb.z, 0.f);
                h[3] = (_Float16)fmaxf(acc[mt][3] + bb.w, 0.f);
                *(half4v*)&H1[myrow * K2P + mt * 16 + qd * 4] = h;
            }
        }
        // wave-private H rows: no block barrier needed between layers

        // ---- layer 2: K=64 (2 steps), out 64 ch ----
        {
            floatx4 acc[4] = {};
#pragma unroll
            for (int ks = 0; ks < 2; ++ks) {
                half8v bf = *(const half8v*)&H1[myrow * K2P + ks * 32 + qd * 8];
#pragma unroll
                for (int mt = 0; mt < 4; ++mt)
                    acc[mt] = __builtin_amdgcn_mfma_f32_16x16x32_f16(a2[ks][mt], bf, acc[mt], 0, 0, 0);
            }
#pragma unroll
            for (int mt = 0; mt < 4; ++mt) {
                float4 bb = *(const float4*)&Lb[64 + mt * 16 + qd * 4];
                half4v h;
                h[0] = (_Float16)fmaxf(acc[mt][0] + bb.x, 0.f);
                h[1] = (_Float16)fmaxf(acc[mt][1] + bb.y, 0.f);
                h[2] = (_Float16)fmaxf(acc[mt][2] + bb.z, 0.f);
                h[3] = (_Float16)fmaxf(acc[mt][3] + bb.w, 0.f);
                *(half4v*)&H2[myrow * K2P + mt * 16 + qd * 4] = h;
            }
        }

        // ---- layer 3 (swapped operands): C rows = neighbors, cols = out-ch ----
        {
            floatx4 acc3[8] = {};
#pragma unroll
            for (int ks = 0; ks < 2; ++ks) {
                half8v av = *(const half8v*)&H2[myrow * K2P + ks * 32 + qd * 8];
#pragma unroll
                for (int mt = 0; mt < 8; ++mt)
                    acc3[mt] = __builtin_amdgcn_mfma_f32_16x16x32_f16(av, a3[ks][mt], acc3[mt], 0, 0, 0);
            }
            const short* np4 = &nbr_s[wv * 16 + qd * 4];
            const bool v0 = np4[0] >= 0, v1 = np4[1] >= 0;
            const bool v2 = np4[2] >= 0, v3 = np4[3] >= 0;
#pragma unroll
            for (int mt = 0; mt < 8; ++mt) {
                float m = v0 ? acc3[mt][0] : -INFINITY;
                m = fmaxf(m, v1 ? acc3[mt][1] : -INFINITY);
                m = fmaxf(m, v2 ? acc3[mt][2] : -INFINITY);
                m = fmaxf(m, v3 ? acc3[mt][3] : -INFINITY);
                m = fmaxf(m, __shfl_xor(m, 16));
                m = fmaxf(m, __shfl_xor(m, 32));
                if (qd == 0) CW[wv * NCO + mt * 16 + c] = m;
            }
        }
        __syncthreads();

        if (tid < NCO) {
            float m = fmaxf(fmaxf(CW[tid], CW[NCO + tid]),
                            fmaxf(CW[2 * NCO + tid], CW[3 * NCO + tid]));
            m += b3r;                               // exact: add after max
            if (nbr_s[NK - 1] < 0) m = fmaxf(m, 0.f);  // ref's masked zeros
            out[(size_t)bs * NCO + tid] = m;
        }
    }
}

extern "C" void kernel_launch(void* const* d_in, const int* in_sizes, int n_in,
                              void* d_out, int out_size, void* d_ws, size_t ws_size,
                              hipStream_t stream) {
    const float* x   = (const float*)d_in[0];
    const float* pos = (const float*)d_in[1];
    const float* W1  = (const float*)d_in[2];
    const float* b1  = (const float*)d_in[3];
    const float* W2  = (const float*)d_in[4];
    const float* b2  = (const float*)d_in[5];
    const float* W3  = (const float*)d_in[6];
    const float* b3  = (const float*)d_in[7];

    float* out0 = (float*)d_out;                       // [B,S,128]
    float* nxyz = out0 + (size_t)NB * NS * NCO;        // [B,S,3]
    short* bidx = (short*)d_ws;                        // [B,S,K] int16 = 1 MB
    _Float16* wtp = (_Float16*)((char*)d_ws + (size_t)NB * NS * NK * sizeof(short));

    wt_kernel<<<256, 64, 0, stream>>>(W1, W2, W3, wtp);
    fps_kernel<<<NB, FPS_T, 0, stream>>>(pos, nxyz);
    ballq_kernel<<<(NB * NS) / 4, 256, 0, stream>>>(pos, nxyz, bidx);
    mlp_kernel<<<NB * NS / QPB, 256, 0, stream>>>(x, pos, b1, b2, b3,
                                                  nxyz, bidx, wtp, out0);
}

// Round 6
// 828.557 us; speedup vs baseline: 1.1300x; 1.1300x over previous
//
#include <hip/hip_runtime.h>
#include <stdint.h>

#define NB 8
#define NP 4096
#define NS 1024
#define NK 64
#define ND 64
#define NH 64
#define NCO 128

#define FPS_T 512
#define PPT (NP / FPS_T)   // 8 points per thread

// padded K strides (in halves) for conflict-free b128 LDS access
#define K1P 104            // layer1 K: 64 x-ch + 3 xyz + zeros to 96, padded to 104
#define K2P 72             // layer2/3 K: 64, padded to 72

#define QPB 16             // queries per block in mlp_kernel

typedef _Float16 half8v __attribute__((ext_vector_type(8)));
typedef _Float16 half4v __attribute__((ext_vector_type(4)));
typedef _Float16 half2v __attribute__((ext_vector_type(2)));
typedef float    floatx4 __attribute__((ext_vector_type(4)));

// DPP move helper (ctrl must be compile-time constant)
template <int CTRL>
__device__ __forceinline__ float dpp_mov_f32(float x) {
    return __int_as_float(__builtin_amdgcn_update_dpp(
        0, __float_as_int(x), CTRL, 0xf, 0xf, true));
}

// ---------------- Kernel 0: weight transpose + f16 convert ----------------
// wt layout (halves): [0)      W1t[64][104]: k<64 -> W1[(3+k)*64+j] (x chans),
//                              k=64..66 -> W1[(k-64)*64+j] (xyz), else 0
//                     [6656)   W2t[64][72]:  k<64 -> W2[k*64+r], else 0
//                     [11264)  W3t[128][72]: k<64 -> W3[k*128+r], else 0
__global__ __launch_bounds__(64) void wt_kernel(const float* __restrict__ W1,
                                                const float* __restrict__ W2,
                                                const float* __restrict__ W3,
                                                _Float16* __restrict__ wt)
{
    const int j = blockIdx.x;
    const int t = threadIdx.x;
    if (j < 64) {
        for (int k = t; k < K1P; k += 64) {
            float v = 0.f;
            if (k < 64)       v = W1[(3 + k) * 64 + j];
            else if (k < 67)  v = W1[(k - 64) * 64 + j];
            wt[j * K1P + k] = (_Float16)v;
        }
    } else if (j < 128) {
        const int r = j - 64;
        for (int k = t; k < K2P; k += 64) {
            float v = (k < 64) ? W2[k * 64 + r] : 0.f;
            wt[6656 + r * K2P + k] = (_Float16)v;
        }
    } else {
        const int r = j - 128;
        for (int k = t; k < K2P; k += 64) {
            float v = (k < 64) ? W3[k * 128 + r] : 0.f;
            wt[11264 + r * K2P + k] = (_Float16)v;
        }
    }
}

// ---------------- Kernel 1: farthest point sampling (R4-proven version) ------
// One block per batch, 512 threads, 8 points/thread in registers.
// Bit-exact fp32 (contract off) so argmax selections match the reference.
// Per step: local update+argmax; wave value-max via DPP (lane 63); winner
// index via ballot+ctz+readlane; cross-wave via packed u64 keys in parity
// double-buffered LDS slots (ONE barrier/step); winner coords via broadcast
// sp[last] b128 read.
__global__ __launch_bounds__(FPS_T) void fps_kernel(const float* __restrict__ pos,
                                                    float* __restrict__ new_xyz)
{
#pragma clang fp contract(off)
    const int b    = blockIdx.x;
    const int tid  = threadIdx.x;
    const int lane = tid & 63;
    const int wv   = tid >> 6;            // 0..7

    __shared__ float4 sp[NP];             // {x,y,z,0} per point, 64 KB
    __shared__ alignas(16) unsigned long long wbuf[2][8];

    const float* p = pos + (size_t)b * NP * 3;
    for (int i = tid; i < NP; i += FPS_T) {
        sp[i] = make_float4(p[i * 3 + 0], p[i * 3 + 1], p[i * 3 + 2], 0.0f);
    }
    __syncthreads();

    float px[PPT], py[PPT], pz[PPT], md[PPT];
#pragma unroll
    for (int j = 0; j < PPT; ++j) {
        float4 v = sp[tid * PPT + j];
        px[j] = v.x; py[j] = v.y; pz[j] = v.z;
        md[j] = 1e10f;
    }

    int last = 0;
    if (tid == 0) {
        float4 v = sp[0];
        float* o = new_xyz + (size_t)b * NS * 3;
        o[0] = v.x; o[1] = v.y; o[2] = v.z;
    }

    int par = 0;
    for (int s = 1; s < NS; ++s) {
        const float4 lp = sp[last];
        const float lx = lp.x, ly = lp.y, lz = lp.z;

        float bv = 0.0f;
        int   bi = tid * PPT;
#pragma unroll
        for (int j = 0; j < PPT; ++j) {
            float dx = px[j] - lx;
            float dy = py[j] - ly;
            float dz = pz[j] - lz;
            float d2 = dx * dx + dy * dy + dz * dz;   // contract(off): exact IEEE
            float m  = (md[j] < d2) ? md[j] : d2;     // jnp.minimum
            md[j] = m;
            if (m > bv) { bv = m; bi = tid * PPT + j; }
        }

        float r = bv;
        r = fmaxf(r, dpp_mov_f32<0x111>(r));   // row_shr:1
        r = fmaxf(r, dpp_mov_f32<0x112>(r));   // row_shr:2
        r = fmaxf(r, dpp_mov_f32<0x114>(r));   // row_shr:4
        r = fmaxf(r, dpp_mov_f32<0x118>(r));   // row_shr:8
        r = fmaxf(r, dpp_mov_f32<0x142>(r));   // row_bcast:15
        r = fmaxf(r, dpp_mov_f32<0x143>(r));   // row_bcast:31
        const float gmax = __int_as_float(
            __builtin_amdgcn_readlane(__float_as_int(r), 63));

        unsigned long long mk = __ballot(bv == gmax);
        int wl = (int)__builtin_ctzll(mk);
        int bw = __builtin_amdgcn_readlane(bi, wl);

        if (lane == 0) {
            wbuf[par][wv] =
                ((unsigned long long)__float_as_uint(gmax) << 32) |
                (unsigned long long)(~(unsigned)bw);
        }
        __syncthreads();

        const ulonglong2* wb = (const ulonglong2*)wbuf[par];
        ulonglong2 q0 = wb[0], q1 = wb[1], q2 = wb[2], q3 = wb[3];
        unsigned long long a0 = (q0.y > q0.x) ? q0.y : q0.x;
        unsigned long long a1 = (q1.y > q1.x) ? q1.y : q1.x;
        unsigned long long a2 = (q2.y > q2.x) ? q2.y : q2.x;
        unsigned long long a3 = (q3.y > q3.x) ? q3.y : q3.x;
        unsigned long long b0 = (a1 > a0) ? a1 : a0;
        unsigned long long b1 = (a3 > a2) ? a3 : a2;
        unsigned long long g  = (b1 > b0) ? b1 : b0;

        last = (int)(~(unsigned)g);
        if (tid == 0) {
            float4 v = sp[last];
            float* o = new_xyz + ((size_t)b * NS + s) * 3;
            o[0] = v.x; o[1] = v.y; o[2] = v.z;
        }
        par ^= 1;
    }
}

// ---------------- Kernel 2: ball query (int16 output) ----------------
__global__ __launch_bounds__(256) void ballq_kernel(const float* __restrict__ pos,
                                                    const float* __restrict__ new_xyz,
                                                    short* __restrict__ ball_idx)
{
#pragma clang fp contract(off)
    const int lane = threadIdx.x & 63;
    const int q    = (blockIdx.x * 256 + threadIdx.x) >> 6;   // 0..NB*NS-1
    const int b    = q >> 10;

    const float* p  = pos + (size_t)b * NP * 3;
    const float  qx = new_xyz[q * 3 + 0];
    const float  qy = new_xyz[q * 3 + 1];
    const float  qz = new_xyz[q * 3 + 2];
    short* outp = ball_idx + (size_t)q * NK;

    int cnt = 0;
    for (int n0 = 0; n0 < NP; n0 += 64) {
        const int n = n0 + lane;
        float dx = qx - p[n * 3 + 0];
        float dy = qy - p[n * 3 + 1];
        float dz = qz - p[n * 3 + 2];
        float d2 = dx * dx + dy * dy + dz * dz;   // contract(off)
        bool within = d2 < 0.04f;                 // r^2, strict <
        unsigned long long m = __ballot(within);
        if (within) {
            int slot = cnt + __popcll(m & ((1ull << lane) - 1ull));
            if (slot < NK) outp[slot] = (short)n;
        }
        cnt += (int)__popcll(m);
        if (cnt >= NK) break;
    }
    if (cnt < NK) {
        if (lane < NK - cnt) outp[cnt + lane] = (short)-1;
    }
}

// ---------------- Kernel 3: persistent gather + f16-MFMA MLP + max-pool ------
// 512 blocks x QPB(16) queries. All 36 weight frags hoisted to registers once
// per block (loaded straight from global wt). Layers 1/2: h^T = W^T x act^T
// (C/D col = neighbor -> packed b64 writes). Layer 3 swaps MFMA operands
// (act as A, W3 as B) so C/D rows = neighbors: pool = 3 in-register fmax +
// xor16/xor32 shuffles. Bias postponed past the pool (exact: fp max/add
// monotone); masked-0 restored via fmax(m,0) when the nbr list has padding.
__global__ __launch_bounds__(256, 2) void mlp_kernel(const float* __restrict__ x,
        const float* __restrict__ pos,
        const float* __restrict__ b1, const float* __restrict__ b2,
        const float* __restrict__ b3,
        const float* __restrict__ new_xyz, const short* __restrict__ ball_idx,
        const _Float16* __restrict__ wt,
        float* __restrict__ out)
{
    const int tid  = threadIdx.x;
    const int lane = tid & 63;
    const int wv   = tid >> 6;
    const int qd   = lane >> 4;       // quad
    const int c    = lane & 15;       // col within MFMA tile
    const int myrow = wv * 16 + c;    // this lane's neighbor row

    __shared__ alignas(16) _Float16 G [64 * K1P];   // gathered input: [nbr][k]
    __shared__ alignas(16) _Float16 H1[64 * K2P];   // h1: [nbr][ch]
    __shared__ alignas(16) _Float16 H2[64 * K2P];   // h2: [nbr][ch]
    __shared__ alignas(16) float    CW[4 * NCO];    // per-wave pooled partials
    __shared__ alignas(16) float    Lb[128];        // b1|b2 staged
    __shared__ short nbr_s[NK];

    // ---- hoist all weight fragments into registers (once per block) ----
    half8v a1[3][4], a2[2][4], a3[2][8];
#pragma unroll
    for (int ks = 0; ks < 3; ++ks)
#pragma unroll
        for (int mt = 0; mt < 4; ++mt)
            a1[ks][mt] = *(const half8v*)&wt[(mt * 16 + c) * K1P + ks * 32 + qd * 8];
#pragma unroll
    for (int ks = 0; ks < 2; ++ks)
#pragma unroll
        for (int mt = 0; mt < 4; ++mt)
            a2[ks][mt] = *(const half8v*)&wt[6656 + (mt * 16 + c) * K2P + ks * 32 + qd * 8];
#pragma unroll
    for (int ks = 0; ks < 2; ++ks)
#pragma unroll
        for (int mt = 0; mt < 8; ++mt)
            a3[ks][mt] = *(const half8v*)&wt[11264 + (mt * 16 + c) * K2P + ks * 32 + qd * 8];

    const float b3r = (tid < NCO) ? b3[tid] : 0.f;
    if (tid < 64) { Lb[tid] = b1[tid]; Lb[64 + tid] = b2[tid]; }
    {   // zero G once; gather never touches cols >= 67 (MFMA pad)
        half8v z = {};
        for (int i = tid; i < (64 * K1P) / 8; i += 256) ((half8v*)G)[i] = z;
    }

    for (int qi = 0; qi < QPB; ++qi) {
        const int bs = blockIdx.x * QPB + qi;
        const int b  = bs >> 10;

        __syncthreads();   // protect G/H/nbr_s/CW reuse from previous query

        // gather: thread -> neighbor tid>>2, x-channel quarter tid&3
        {
            const int ni = tid >> 2;
            const int p4 = tid & 3;
            const int n  = (int)ball_idx[(size_t)bs * NK + ni];
            const int nn = (n < 0) ? (NP - 1) : n;    // ref: points[-1] padding
            const float* xr = x + ((size_t)b * NP + nn) * ND + p4 * 16;
#pragma unroll
            for (int i = 0; i < 4; ++i) {
                float4 v = *(const float4*)(xr + 4 * i);
                half4v h;
                h[0] = (_Float16)v.x; h[1] = (_Float16)v.y;
                h[2] = (_Float16)v.z; h[3] = (_Float16)v.w;
                *(half4v*)&G[ni * K1P + p4 * 16 + 4 * i] = h;
            }
            if (p4 == 3) nbr_s[ni] = (short)n;
            if (p4 == 0) {
                const float* pr = pos + (size_t)(b * NP + nn) * 3;
                float gx = pr[0] - new_xyz[bs * 3 + 0];
                float gy = pr[1] - new_xyz[bs * 3 + 1];
                float gz = pr[2] - new_xyz[bs * 3 + 2];
                half2v h2; h2[0] = (_Float16)gx; h2[1] = (_Float16)gy;
                *(half2v*)&G[ni * K1P + 64] = h2;
                G[ni * K1P + 66] = (_Float16)gz;
            }
        }
        __syncthreads();

        // ---- layer 1: K=96 (3 steps), out 64 ch ----
        {
            floatx4 acc[4] = {};
#pragma unroll
            for (int ks = 0; ks < 3; ++ks) {
                half8v bf = *(const half8v*)&G[myrow * K1P + ks * 32 + qd * 8];
#pragma unroll
                for (int mt = 0; mt < 4; ++mt)
                    acc[mt] = __builtin_amdgcn_mfma_f32_16x16x32_f16(a1[ks][mt], bf, acc[mt], 0, 0, 0);
            }
#pragma unroll
            for (int mt = 0; mt < 4; ++mt) {
                float4 bb = *(const float4*)&Lb[mt * 16 + qd * 4];
                half4v h;
                h[0] = (_Float16)fmaxf(acc[mt][0] + bb.x, 0.f);
                h[1] = (_Float16)fmaxf(acc[mt][1] + bb.y, 0.f);
                h[2] = (_Float16)fmaxf(acc[mt][2] + bb.z, 0.f);
                h[3] = (_Float16)fmaxf(acc[mt][3] + bb.w, 0.f);
                *(half4v*)&H1[myrow * K2P + mt * 16 + qd * 4] = h;
            }
        }
        // wave-private H rows: no block barrier needed between layers

        // ---- layer 2: K=64 (2 steps), out 64 ch ----
        {
            floatx4 acc[4] = {};
#pragma unroll
            for (int ks = 0; ks < 2; ++ks) {
                half8v bf = *(const half8v*)&H1[myrow * K2P + ks * 32 + qd * 8];
#pragma unroll
                for (int mt = 0; mt < 4; ++mt)
                    acc[mt] = __builtin_amdgcn_mfma_f32_16x16x32_f16(a2[ks][mt], bf, acc[mt], 0, 0, 0);
            }
#pragma unroll
            for (int mt = 0; mt < 4; ++mt) {
                float4 bb = *(const float4*)&Lb[64 + mt * 16 + qd * 4];
                half4v h;
                h[0] = (_Float16)fmaxf(acc[mt][0] + bb.x, 0.f);
                h[1] = (_Float16)fmaxf(acc[mt][1] + bb.y, 0.f);
                h[2] = (_Float16)fmaxf(acc[mt][2] + bb.z, 0.f);
                h[3] = (_Float16)fmaxf(acc[mt][3] + bb.w, 0.f);
                *(half4v*)&H2[myrow * K2P + mt * 16 + qd * 4] = h;
            }
        }

        // ---- layer 3 (swapped operands): C rows = neighbors, cols = out-ch ----
        {
            floatx4 acc3[8] = {};
#pragma unroll
            for (int ks = 0; ks < 2; ++ks) {
                half8v av = *(const half8v*)&H2[myrow * K2P + ks * 32 + qd * 8];
#pragma unroll
                for (int mt = 0; mt < 8; ++mt)
                    acc3[mt] = __builtin_amdgcn_mfma_f32_16x16x32_f16(av, a3[ks][mt], acc3[mt], 0, 0, 0);
            }
            const short* np4 = &nbr_s[wv * 16 + qd * 4];
            const bool v0 = np4[0] >= 0, v1 = np4[1] >= 0;
            const bool v2 = np4[2] >= 0, v3 = np4[3] >= 0;
#pragma unroll
            for (int mt = 0; mt < 8; ++mt) {
                float m = v0 ? acc3[mt][0] : -INFINITY;
                m = fmaxf(m, v1 ? acc3[mt][1] : -INFINITY);
                m = fmaxf(m, v2 ? acc3[mt][2] : -INFINITY);
                m = fmaxf(m, v3 ? acc3[mt][3] : -INFINITY);
                m = fmaxf(m, __shfl_xor(m, 16));
                m = fmaxf(m, __shfl_xor(m, 32));
                if (qd == 0) CW[wv * NCO + mt * 16 + c] = m;
            }
        }
        __syncthreads();

        if (tid < NCO) {
            float m = fmaxf(fmaxf(CW[tid], CW[NCO + tid]),
                            fmaxf(CW[2 * NCO + tid], CW[3 * NCO + tid]));
            m += b3r;                               // exact: add after max
            if (nbr_s[NK - 1] < 0) m = fmaxf(m, 0.f);  // ref's masked zeros
            out[(size_t)bs * NCO + tid] = m;
        }
    }
}

extern "C" void kernel_launch(void* const* d_in, const int* in_sizes, int n_in,
                              void* d_out, int out_size, void* d_ws, size_t ws_size,
                              hipStream_t stream) {
    const float* x   = (const float*)d_in[0];
    const float* pos = (const float*)d_in[1];
    const float* W1  = (const float*)d_in[2];
    const float* b1  = (const float*)d_in[3];
    const float* W2  = (const float*)d_in[4];
    const float* b2  = (const float*)d_in[5];
    const float* W3  = (const float*)d_in[6];
    const float* b3  = (const float*)d_in[7];

    float* out0 = (float*)d_out;                       // [B,S,128]
    float* nxyz = out0 + (size_t)NB * NS * NCO;        // [B,S,3]
    short* bidx = (short*)d_ws;                        // [B,S,K] int16 = 1 MB
    _Float16* wtp = (_Float16*)((char*)d_ws + (size_t)NB * NS * NK * sizeof(short));

    wt_kernel<<<256, 64, 0, stream>>>(W1, W2, W3, wtp);
    fps_kernel<<<NB, FPS_T, 0, stream>>>(pos, nxyz);
    ballq_kernel<<<(NB * NS) / 4, 256, 0, stream>>>(pos, nxyz, bidx);
    mlp_kernel<<<NB * NS / QPB, 256, 0, stream>>>(x, pos, b1, b2, b3,
                                                  nxyz, bidx, wtp, out0);
}